// Round 1
// baseline (484.101 us; speedup 1.0000x reference)
//
#include <hip/hip_runtime.h>
#include <math.h>

#define D_IN   256
#define D_E    64
#define N_SUP  16384
#define NQ     256
#define KSEL   32
#define RTOLC  1e-5f
#define ATOLC  1e-5f
#define INV_T  10.0f   // 1/TEMPERATURE

__device__ __forceinline__ float gelu_exact(float x) {
    // jax.nn.gelu(approximate=False): x * 0.5 * (1 + erf(x/sqrt(2)))
    return 0.5f * x * (1.0f + erff(x * 0.70710678118654752440f));
}

// One wave (64 lanes) per row; lane = output feature. Block = 4 waves = 4 rows.
__global__ __launch_bounds__(256) void embed_kernel(
    const float* __restrict__ X, int M,
    const float* __restrict__ W1, const float* __restrict__ b1,
    const float* __restrict__ W2, const float* __restrict__ b2,
    const float* __restrict__ W3, const float* __restrict__ b3,
    float* __restrict__ E, float* __restrict__ norms)
{
    const int wave = threadIdx.x >> 6;
    const int lane = threadIdx.x & 63;
    const int row  = blockIdx.x * 4 + wave;
    const bool valid = row < M;

    __shared__ float xs[4][D_IN];
    __shared__ float hs[4][D_E];

    if (valid) {
        #pragma unroll
        for (int i = 0; i < 4; ++i)
            xs[wave][lane + 64 * i] = X[row * D_IN + lane + 64 * i];
    }
    __syncthreads();

    float h = 0.0f;
    if (valid) {
        float acc = b1[lane];
        const float* w1r = W1 + lane * D_IN;
        #pragma unroll 8
        for (int k = 0; k < D_IN; ++k)
            acc = fmaf(w1r[k], xs[wave][k], acc);
        h = gelu_exact(acc);
    }
    __syncthreads();
    if (valid) hs[wave][lane] = h;
    __syncthreads();

    if (valid) {
        float acc = b2[lane];
        const float* w2r = W2 + lane * D_E;
        #pragma unroll 8
        for (int k = 0; k < D_E; ++k)
            acc = fmaf(w2r[k], hs[wave][k], acc);
        h = gelu_exact(acc);
    }
    __syncthreads();
    if (valid) hs[wave][lane] = h;
    __syncthreads();

    float e = 0.0f;
    if (valid) {
        float acc = b3[lane];
        const float* w3r = W3 + lane * D_E;
        #pragma unroll 8
        for (int k = 0; k < D_E; ++k)
            acc = fmaf(w3r[k], hs[wave][k], acc);
        e = 1.0f / (1.0f + expf(-acc));
        E[row * D_E + lane] = e;
    }
    // wave-reduce sum of e^2 for the norm
    float nn = e * e;
    #pragma unroll
    for (int off = 32; off > 0; off >>= 1)
        nn += __shfl_down(nn, off);
    if (valid && lane == 0) norms[row] = nn;
}

// One block (256 threads) per query. Distances staged in LDS, then 32 rounds
// of block-wide argmin (tie -> lowest index, matching jax.lax.top_k), with
// online softmax accumulation on thread 0.
__global__ __launch_bounds__(256) void knn_kernel(
    const float* __restrict__ s_emb, const float* __restrict__ s_norm,
    const float* __restrict__ q_emb, const float* __restrict__ q_norm,
    const float* __restrict__ labels, float* __restrict__ out)
{
    __shared__ float dist[N_SUP];       // 64 KB
    __shared__ float qv[D_E];
    __shared__ float red_v[4];
    __shared__ int   red_i[4];
    __shared__ float s_qn;

    const int tid = threadIdx.x;
    const int qi  = blockIdx.x;

    if (tid < D_E) qv[tid] = q_emb[qi * D_E + tid];
    if (tid == 0)  s_qn = q_norm[qi];
    __syncthreads();
    const float qn = s_qn;

    // distance + isclose mask
    for (int j = tid; j < N_SUP; j += 256) {
        const float* srow = s_emb + j * D_E;
        float dot = 0.0f;
        bool close = true;
        #pragma unroll 8
        for (int d = 0; d < D_E; ++d) {
            float sv = srow[d];
            float qd = qv[d];
            dot = fmaf(qd, sv, dot);
            close = close && (fabsf(qd - sv) <= (ATOLC + RTOLC * fabsf(sv)));
        }
        float d2 = qn + s_norm[j] - 2.0f * dot;
        float dd = sqrtf(fmaxf(d2, 0.0f));
        dist[j] = close ? INFINITY : dd;
    }
    __syncthreads();

    const int wave = tid >> 6;
    const int lane = tid & 63;
    float d0 = 0.0f, sumw = 0.0f, accl = 0.0f;   // live on thread 0

    for (int it = 0; it < KSEL; ++it) {
        // per-thread strided scan: strict < keeps the smallest index on ties
        float bv = INFINITY;
        int   bi = N_SUP;
        for (int j = tid; j < N_SUP; j += 256) {
            float v = dist[j];
            if (v < bv) { bv = v; bi = j; }
        }
        // wave reduce (64 lanes), tie -> smaller index
        #pragma unroll
        for (int off = 32; off > 0; off >>= 1) {
            float ov = __shfl_down(bv, off);
            int   oi = __shfl_down(bi, off);
            if (ov < bv || (ov == bv && oi < bi)) { bv = ov; bi = oi; }
        }
        if (lane == 0) { red_v[wave] = bv; red_i[wave] = bi; }
        __syncthreads();
        if (tid == 0) {
            float dmin = red_v[0]; int jmin = red_i[0];
            #pragma unroll
            for (int w = 1; w < 4; ++w) {
                float ov = red_v[w]; int oi = red_i[w];
                if (ov < dmin || (ov == dmin && oi < jmin)) { dmin = ov; jmin = oi; }
            }
            if (jmin >= N_SUP) jmin = 0;     // safety (cannot trigger: K << finite count)
            if (it == 0) d0 = dmin;
            float w = expf((d0 - dmin) * INV_T);   // exp(-(d-d0)/T); inf -> 0
            sumw += w;
            accl += w * labels[jmin];
            dist[jmin] = INFINITY;            // consume
        }
        __syncthreads();
    }

    if (tid == 0) out[qi] = accl / sumw;
}

extern "C" void kernel_launch(void* const* d_in, const int* in_sizes, int n_in,
                              void* d_out, int out_size, void* d_ws, size_t ws_size,
                              hipStream_t stream) {
    const float* x      = (const float*)d_in[0];   // [256,256]
    const float* sx     = (const float*)d_in[1];   // [16384,256]
    const float* labels = (const float*)d_in[2];   // [16384,1]
    const float* W1     = (const float*)d_in[3];   // [64,256]
    const float* b1     = (const float*)d_in[4];   // [64]
    const float* W2     = (const float*)d_in[5];   // [64,64]
    const float* b2     = (const float*)d_in[6];   // [64]
    const float* W3     = (const float*)d_in[7];   // [64,64]
    const float* b3     = (const float*)d_in[8];   // [64]
    float* out = (float*)d_out;

    float* ws     = (float*)d_ws;
    float* s_emb  = ws;                       // 16384*64
    float* s_norm = s_emb + N_SUP * D_E;      // 16384
    float* q_emb  = s_norm + N_SUP;           // 256*64
    float* q_norm = q_emb + NQ * D_E;         // 256

    embed_kernel<<<N_SUP / 4, 256, 0, stream>>>(sx, N_SUP, W1, b1, W2, b2, W3, b3,
                                                s_emb, s_norm);
    embed_kernel<<<NQ / 4, 256, 0, stream>>>(x, NQ, W1, b1, W2, b2, W3, b3,
                                             q_emb, q_norm);
    knn_kernel<<<NQ, 256, 0, stream>>>(s_emb, s_norm, q_emb, q_norm, labels, out);
}

// Round 2
// 458.087 us; speedup vs baseline: 1.0568x; 1.0568x over previous
//
#include <hip/hip_runtime.h>
#include <math.h>

#define D_IN   256
#define D_E    64
#define N_SUP  16384
#define NQ     256
#define KSEL   32
#define RTOLC  1e-5f
#define ATOLC  1e-5f
#define INV_T  10.0f   // 1/TEMPERATURE

typedef unsigned long long ull;

__device__ __forceinline__ float gelu_exact(float x) {
    // jax.nn.gelu(approximate=False): x * 0.5 * (1 + erf(x/sqrt(2)))
    return 0.5f * x * (1.0f + erff(x * 0.70710678118654752440f));
}

// Block = 256 threads = 4 waves, handles 64 rows (lane = row).
// Wave w computes output features [w*16, w*16+16) of each layer; W accesses are
// wave-uniform (readfirstlane -> SGPR s_load), x streams per-lane as float4.
__global__ __launch_bounds__(256) void embed_kernel(
    const float* __restrict__ X,
    const float* __restrict__ W1, const float* __restrict__ b1,
    const float* __restrict__ W2, const float* __restrict__ b2,
    const float* __restrict__ W3, const float* __restrict__ b3,
    float* __restrict__ E, float* __restrict__ norms)
{
    const int lane = threadIdx.x & 63;
    const int wv   = threadIdx.x >> 6;
    const int f0   = __builtin_amdgcn_readfirstlane(wv * 16);   // SGPR-uniform
    const int row  = blockIdx.x * 64 + lane;

    __shared__ float hx[64][65];     // padded: bank = (lane+f)%32, 2-way (free)
    __shared__ float nsum[64][5];

    // ---- layer 1: h[f] = gelu(b1[f] + sum_k W1[f][k]*x[row][k]), k ascending
    float acc[16];
    #pragma unroll
    for (int i = 0; i < 16; ++i) acc[i] = b1[f0 + i];

    const float* xrow = X + (size_t)row * D_IN;
    #pragma unroll
    for (int kt = 0; kt < D_IN; kt += 64) {
        float4 xv[16];
        #pragma unroll
        for (int i = 0; i < 16; ++i)
            xv[i] = *reinterpret_cast<const float4*>(xrow + kt + 4 * i);
        #pragma unroll
        for (int f = 0; f < 16; ++f) {
            const float* wr = W1 + (size_t)(f0 + f) * D_IN + kt;   // uniform -> s_load
            #pragma unroll
            for (int i = 0; i < 16; ++i) {
                acc[f] = fmaf(wr[4*i+0], xv[i].x, acc[f]);
                acc[f] = fmaf(wr[4*i+1], xv[i].y, acc[f]);
                acc[f] = fmaf(wr[4*i+2], xv[i].z, acc[f]);
                acc[f] = fmaf(wr[4*i+3], xv[i].w, acc[f]);
            }
        }
    }
    #pragma unroll
    for (int i = 0; i < 16; ++i) hx[lane][f0 + i] = gelu_exact(acc[i]);
    __syncthreads();                       // L1 h visible

    // ---- layer 2
    float hreg[64];
    #pragma unroll
    for (int f = 0; f < D_E; ++f) hreg[f] = hx[lane][f];
    __syncthreads();                       // all reads done before overwrite
    float acc2[16];
    #pragma unroll
    for (int i = 0; i < 16; ++i) {
        float a = b2[f0 + i];
        const float* wr = W2 + (size_t)(f0 + i) * D_E;             // uniform -> s_load
        #pragma unroll
        for (int f = 0; f < D_E; ++f) a = fmaf(wr[f], hreg[f], a);
        acc2[i] = gelu_exact(a);
    }
    #pragma unroll
    for (int i = 0; i < 16; ++i) hx[lane][f0 + i] = acc2[i];
    __syncthreads();                       // L2 h visible

    // ---- layer 3 + sigmoid
    #pragma unroll
    for (int f = 0; f < D_E; ++f) hreg[f] = hx[lane][f];
    float e[16];
    float np = 0.0f;
    #pragma unroll
    for (int i = 0; i < 16; ++i) {
        float a = b3[f0 + i];
        const float* wr = W3 + (size_t)(f0 + i) * D_E;             // uniform -> s_load
        #pragma unroll
        for (int f = 0; f < D_E; ++f) a = fmaf(wr[f], hreg[f], a);
        e[i] = 1.0f / (1.0f + expf(-a));
        np = fmaf(e[i], e[i], np);
    }
    float* erow = E + (size_t)row * D_E + f0;
    #pragma unroll
    for (int i = 0; i < 4; ++i)
        *reinterpret_cast<float4*>(erow + 4 * i) =
            make_float4(e[4*i], e[4*i+1], e[4*i+2], e[4*i+3]);

    nsum[lane][wv] = np;
    __syncthreads();
    if (wv == 0)
        norms[row] = nsum[lane][0] + nsum[lane][1] + nsum[lane][2] + nsum[lane][3];
}

// One block (1024 threads = 16 waves) per query. Each thread owns 16 support
// rows, keeps d^2 in registers; top-32 via iterative block-argmin over packed
// (float-bits, index) uint64 keys (exact jax top_k tie semantics: lower index
// wins on equal distance).
__global__ __launch_bounds__(1024) void knn_kernel(
    const float* __restrict__ s_emb, const float* __restrict__ s_norm,
    const float* __restrict__ q_emb, const float* __restrict__ q_norm,
    const float* __restrict__ labels, float* __restrict__ out)
{
    __shared__ float qv[D_E];
    __shared__ ull   wmin[16];
    __shared__ ull   s_win;
    __shared__ ull   winners[KSEL];

    const int tid  = threadIdx.x;
    const int lane = tid & 63;
    const int wid  = tid >> 6;
    const int qi   = blockIdx.x;

    if (tid < D_E) qv[tid] = q_emb[qi * D_E + tid];
    __syncthreads();
    const float qn = q_norm[qi];

    const int row0 = tid * 16;
    float d2v[16];
    ull key = ~0ull;

    #pragma unroll
    for (int i = 0; i < 16; ++i) {
        const float* srow = s_emb + (size_t)(row0 + i) * D_E;
        float dot = 0.0f;
        #pragma unroll
        for (int k = 0; k < D_E; k += 4) {
            float4 sv = *reinterpret_cast<const float4*>(srow + k);
            float4 qk = *reinterpret_cast<const float4*>(&qv[k]);
            dot = fmaf(qk.x, sv.x, dot);
            dot = fmaf(qk.y, sv.y, dot);
            dot = fmaf(qk.z, sv.z, dot);
            dot = fmaf(qk.w, sv.w, dot);
        }
        float d2 = qn + s_norm[row0 + i] - 2.0f * dot;
        d2 = fmaxf(d2, 0.0f);
        if (d2 < 1e-2f) {
            // possible isclose-duplicate (true mask requires d2 <= 2.6e-8;
            // 1e-2 gate is slack for fp cancellation in qn+sn-2dot)
            bool close = true;
            #pragma unroll
            for (int k = 0; k < D_E; ++k) {
                float sv = srow[k];
                close = close && (fabsf(qv[k] - sv) <= (ATOLC + RTOLC * fabsf(sv)));
            }
            if (close) d2 = INFINITY;
        }
        d2v[i] = d2;
        ull kk = ((ull)__float_as_uint(d2) << 32) | (unsigned)(row0 + i);
        key = kk < key ? kk : key;
    }

    for (int it = 0; it < KSEL; ++it) {
        // wave argmin (packed keys: lexicographic (d2, idx) min)
        ull kk = key;
        #pragma unroll
        for (int off = 32; off > 0; off >>= 1) {
            ull o = __shfl_down(kk, off);
            kk = o < kk ? o : kk;
        }
        if (lane == 0) wmin[wid] = kk;
        __syncthreads();
        // stage 2: full wave 0 active (no inactive-lane shuffle garbage)
        if (wid == 0) {
            ull k2 = (lane < 16) ? wmin[lane] : ~0ull;
            #pragma unroll
            for (int off = 8; off > 0; off >>= 1) {
                ull o = __shfl_down(k2, off);
                k2 = o < k2 ? o : k2;
            }
            if (lane == 0) { s_win = k2; winners[it] = k2; }
        }
        __syncthreads();
        const ull w = s_win;
        const unsigned widx = (unsigned)(w & 0xffffffffull);
        if ((int)(widx >> 4) == tid) {
            const int sub = (int)(widx & 15u);
            #pragma unroll
            for (int i = 0; i < 16; ++i)
                if (i == sub) d2v[i] = INFINITY;     // static index, runtime cmp
            ull nk = ~0ull;
            #pragma unroll
            for (int i = 0; i < 16; ++i) {
                ull c = ((ull)__float_as_uint(d2v[i]) << 32) | (unsigned)(row0 + i);
                nk = c < nk ? c : nk;
            }
            key = nk;
        }
    }
    __syncthreads();

    // epilogue: 32 parallel label loads + weight compute, wave-reduce
    if (tid < 64) {
        ull w0 = winners[0];
        float d0 = sqrtf(__uint_as_float((unsigned)(w0 >> 32)));
        float wt = 0.0f, wl = 0.0f;
        if (tid < KSEL) {
            ull w = winners[tid];
            float d = sqrtf(__uint_as_float((unsigned)(w >> 32)));
            wt = expf((d0 - d) * INV_T);
            wl = wt * labels[(unsigned)(w & 0xffffffffull)];
        }
        #pragma unroll
        for (int off = 32; off > 0; off >>= 1) {
            wt += __shfl_down(wt, off);
            wl += __shfl_down(wl, off);
        }
        if (tid == 0) out[qi] = wl / wt;
    }
}

extern "C" void kernel_launch(void* const* d_in, const int* in_sizes, int n_in,
                              void* d_out, int out_size, void* d_ws, size_t ws_size,
                              hipStream_t stream) {
    const float* x      = (const float*)d_in[0];   // [256,256]
    const float* sx     = (const float*)d_in[1];   // [16384,256]
    const float* labels = (const float*)d_in[2];   // [16384,1]
    const float* W1     = (const float*)d_in[3];   // [64,256]
    const float* b1     = (const float*)d_in[4];   // [64]
    const float* W2     = (const float*)d_in[5];   // [64,64]
    const float* b2     = (const float*)d_in[6];   // [64]
    const float* W3     = (const float*)d_in[7];   // [64,64]
    const float* b3     = (const float*)d_in[8];   // [64]
    float* out = (float*)d_out;

    float* ws     = (float*)d_ws;
    float* s_emb  = ws;                       // 16384*64
    float* s_norm = s_emb + N_SUP * D_E;      // 16384
    float* q_emb  = s_norm + N_SUP;           // 256*64
    float* q_norm = q_emb + NQ * D_E;         // 256

    embed_kernel<<<N_SUP / 64, 256, 0, stream>>>(sx, W1, b1, W2, b2, W3, b3,
                                                 s_emb, s_norm);
    embed_kernel<<<NQ / 64, 256, 0, stream>>>(x, W1, b1, W2, b2, W3, b3,
                                              q_emb, q_norm);
    knn_kernel<<<NQ, 1024, 0, stream>>>(s_emb, s_norm, q_emb, q_norm, labels, out);
}

// Round 3
// 160.172 us; speedup vs baseline: 3.0224x; 2.8600x over previous
//
#include <hip/hip_runtime.h>
#include <math.h>

#define D_IN   256
#define D_E    64
#define N_SUP  16384
#define NQ     256
#define KSEL   32
#define RTOLC  1e-5f
#define ATOLC  1e-5f
#define INV_T  10.0f    // 1/TEMPERATURE

#define CHUNK  2048     // support rows per phase-A block
#define NCH    8        // support chunks
#define QG     8        // queries per phase-A block
#define NQG    32       // query groups

typedef unsigned long long ull;

__device__ __forceinline__ float gelu_exact(float x) {
    return 0.5f * x * (1.0f + erff(x * 0.70710678118654752440f));
}

// ---------------------------------------------------------------------------
// Prep: transpose weights so embed's k-loop reads W*T[k][f] with one uniform
// s_load_dwordx16 per k. 3 blocks x 1024 threads (coalesced read, scatter write).
__global__ __launch_bounds__(1024) void prep_transpose(
    const float* __restrict__ W1, const float* __restrict__ W2,
    const float* __restrict__ W3,
    float* __restrict__ W1T, float* __restrict__ W2T, float* __restrict__ W3T)
{
    const int t = threadIdx.x;
    if (blockIdx.x == 0) {
        for (int o = t; o < D_E * D_IN; o += 1024) {
            int f = o >> 8, k = o & 255;               // W1[f][k]
            W1T[k * D_E + f] = W1[o];
        }
    } else if (blockIdx.x == 1) {
        for (int o = t; o < D_E * D_E; o += 1024) {
            int f = o >> 6, k = o & 63;
            W2T[k * D_E + f] = W2[o];
        }
    } else {
        for (int o = t; o < D_E * D_E; o += 1024) {
            int f = o >> 6, k = o & 63;
            W3T[k * D_E + f] = W3[o];
        }
    }
}

// ---------------------------------------------------------------------------
// Embed: 260 blocks x 256 threads. Blocks 0..255 -> support rows, 256..259 ->
// query rows. lane = row (64 rows/block), wave w computes features [16w,16w+16).
// x staged transposed in LDS (coalesced global load, conflict-free k-reads);
// W*T rows are wave-uniform -> s_load. Summation order matches R2 bit-for-bit.
__global__ __launch_bounds__(256) void embed_kernel(
    const float* __restrict__ sx, const float* __restrict__ x,
    const float* __restrict__ W1T, const float* __restrict__ b1,
    const float* __restrict__ W2T, const float* __restrict__ b2,
    const float* __restrict__ W3T, const float* __restrict__ b3,
    float* __restrict__ s_emb, float* __restrict__ s_norm,
    float* __restrict__ q_emb, float* __restrict__ q_norm)
{
    __shared__ float xT[D_IN][65];   // [k][row], pad 65: reads conflict-free
    __shared__ float hA[D_E][65];
    __shared__ float hB[D_E][65];
    __shared__ float nsum[64][4];

    const int lane = threadIdx.x & 63;
    const int wv   = threadIdx.x >> 6;
    const int f0   = __builtin_amdgcn_readfirstlane(wv * 16);
    const bool isq = blockIdx.x >= (N_SUP / 64);
    const float* src = isq ? (x + (size_t)(blockIdx.x - N_SUP / 64) * 64 * D_IN)
                           : (sx + (size_t)blockIdx.x * 64 * D_IN);

    // stage x transposed (coalesced float4 loads)
    #pragma unroll
    for (int i = 0; i < 16; ++i) {
        int f4 = threadIdx.x + 256 * i;
        float4 v = *reinterpret_cast<const float4*>(src + (size_t)f4 * 4);
        int row = f4 >> 6;
        int k0  = (f4 & 63) * 4;
        xT[k0 + 0][row] = v.x; xT[k0 + 1][row] = v.y;
        xT[k0 + 2][row] = v.z; xT[k0 + 3][row] = v.w;
    }
    __syncthreads();

    // layer 1: k ascending per feature (bit-identical chain to R2)
    float acc[16];
    #pragma unroll
    for (int i = 0; i < 16; ++i) acc[i] = b1[f0 + i];
    #pragma unroll 4
    for (int k = 0; k < D_IN; ++k) {
        float xk = xT[k][lane];
        const float* wk = W1T + k * D_E + f0;     // uniform -> s_load
        #pragma unroll
        for (int i = 0; i < 16; ++i) acc[i] = fmaf(wk[i], xk, acc[i]);
    }
    #pragma unroll
    for (int i = 0; i < 16; ++i) hA[f0 + i][lane] = gelu_exact(acc[i]);
    __syncthreads();

    // layer 2
    float a2[16];
    #pragma unroll
    for (int i = 0; i < 16; ++i) a2[i] = b2[f0 + i];
    #pragma unroll 4
    for (int k = 0; k < D_E; ++k) {
        float hk = hA[k][lane];
        const float* wk = W2T + k * D_E + f0;
        #pragma unroll
        for (int i = 0; i < 16; ++i) a2[i] = fmaf(wk[i], hk, a2[i]);
    }
    #pragma unroll
    for (int i = 0; i < 16; ++i) hB[f0 + i][lane] = gelu_exact(a2[i]);
    __syncthreads();

    // layer 3 + sigmoid + norm
    float a3[16];
    #pragma unroll
    for (int i = 0; i < 16; ++i) a3[i] = b3[f0 + i];
    #pragma unroll 4
    for (int k = 0; k < D_E; ++k) {
        float hk = hB[k][lane];
        const float* wk = W3T + k * D_E + f0;
        #pragma unroll
        for (int i = 0; i < 16; ++i) a3[i] = fmaf(wk[i], hk, a3[i]);
    }
    float e[16];
    float np = 0.0f;
    #pragma unroll
    for (int i = 0; i < 16; ++i) {
        e[i] = 1.0f / (1.0f + expf(-a3[i]));
        np = fmaf(e[i], e[i], np);
    }

    const int rowl = isq ? (blockIdx.x - N_SUP / 64) * 64 + lane
                         : blockIdx.x * 64 + lane;
    float* E   = isq ? q_emb  : s_emb;
    float* Nrm = isq ? q_norm : s_norm;
    float* erow = E + (size_t)rowl * D_E + f0;
    #pragma unroll
    for (int i = 0; i < 4; ++i)
        *reinterpret_cast<float4*>(erow + 4 * i) =
            make_float4(e[4*i], e[4*i+1], e[4*i+2], e[4*i+3]);

    nsum[lane][wv] = np;
    __syncthreads();
    if (wv == 0)
        Nrm[rowl] = nsum[lane][0] + nsum[lane][1] + nsum[lane][2] + nsum[lane][3];
}

// ---------------------------------------------------------------------------
// Phase A: grid = NQG*NCH blocks (qg = b>>3, sc = b&7), 1024 threads.
// Each thread computes d^2 for 2 support rows x 8 queries (chunk read once per
// block), writes to d2lds; then 2-wave teams (per query) do register-resident
// per-wave top-32 with packed (d2bits,globalrow) u64 keys; 2-list merge ->
// sorted per-chunk top-32 candidates in ws.
__global__ __launch_bounds__(1024, 4) void knn_phaseA(
    const float* __restrict__ s_emb, const float* __restrict__ s_norm,
    const float* __restrict__ q_emb, const float* __restrict__ q_norm,
    ull* __restrict__ cand)
{
    __shared__ __align__(16) float qs[QG][D_E];
    __shared__ float qn_l[QG];
    __shared__ float d2lds[QG][CHUNK];          // 64 KB
    __shared__ ull   wl[16][KSEL];              // per-wave sorted top-32

    const int tid  = threadIdx.x;
    const int lane = tid & 63;
    const int wid  = tid >> 6;
    const int qg   = blockIdx.x >> 3;
    const int sc   = blockIdx.x & 7;

    if (tid < QG * D_E) ((float*)qs)[tid] = q_emb[qg * QG * D_E + tid];
    if (tid < QG)       qn_l[tid] = q_norm[qg * QG + tid];
    __syncthreads();

    // ---- distances: rows 2*tid, 2*tid+1 of this chunk, all 8 queries
    {
        const int r0 = 2 * tid;
        const int gr0 = sc * CHUNK + r0;
        const float* s0 = s_emb + (size_t)gr0 * D_E;
        const float* s1 = s0 + D_E;
        float acc0[QG], acc1[QG];
        #pragma unroll
        for (int q = 0; q < QG; ++q) { acc0[q] = 0.0f; acc1[q] = 0.0f; }
        #pragma unroll 4
        for (int kq = 0; kq < 16; ++kq) {
            float4 a = *reinterpret_cast<const float4*>(s0 + kq * 4);
            float4 b = *reinterpret_cast<const float4*>(s1 + kq * 4);
            #pragma unroll
            for (int q = 0; q < QG; ++q) {
                float4 qv = *reinterpret_cast<const float4*>(&qs[q][kq * 4]);
                acc0[q] = fmaf(qv.x, a.x, acc0[q]);
                acc0[q] = fmaf(qv.y, a.y, acc0[q]);
                acc0[q] = fmaf(qv.z, a.z, acc0[q]);
                acc0[q] = fmaf(qv.w, a.w, acc0[q]);
                acc1[q] = fmaf(qv.x, b.x, acc1[q]);
                acc1[q] = fmaf(qv.y, b.y, acc1[q]);
                acc1[q] = fmaf(qv.z, b.z, acc1[q]);
                acc1[q] = fmaf(qv.w, b.w, acc1[q]);
            }
        }
        const float sn0 = s_norm[gr0];
        const float sn1 = s_norm[gr0 + 1];
        #pragma unroll
        for (int q = 0; q < QG; ++q) {
            float d2a = fmaxf(qn_l[q] + sn0 - 2.0f * acc0[q], 0.0f);
            float d2b = fmaxf(qn_l[q] + sn1 - 2.0f * acc1[q], 0.0f);
            if (d2a < 1e-2f) {          // possible isclose duplicate (slack gate)
                bool close = true;
                for (int k = 0; k < D_E; ++k) {
                    float sv = s0[k];
                    close = close && (fabsf(qs[q][k] - sv) <= (ATOLC + RTOLC * fabsf(sv)));
                }
                if (close) d2a = INFINITY;
            }
            if (d2b < 1e-2f) {
                bool close = true;
                for (int k = 0; k < D_E; ++k) {
                    float sv = s1[k];
                    close = close && (fabsf(qs[q][k] - sv) <= (ATOLC + RTOLC * fabsf(sv)));
                }
                if (close) d2b = INFINITY;
            }
            d2lds[q][r0]     = d2a;
            d2lds[q][r0 + 1] = d2b;
        }
    }
    __syncthreads();

    // ---- per-wave top-32 (team: waves 2q, 2q+1 own query q)
    {
        const int q    = wid >> 1;
        const int half = wid & 1;
        const int base = sc * CHUNK + half * 64 + lane;   // global row of j=0
        float d2v[16];
        #pragma unroll
        for (int j = 0; j < 16; ++j)
            d2v[j] = d2lds[q][j * 128 + half * 64 + lane];

        unsigned mask = 0;
        ull key = ~0ull;
        #pragma unroll
        for (int j = 0; j < 16; ++j) {
            ull c = ((ull)__float_as_uint(d2v[j]) << 32) | (unsigned)(base + j * 128);
            key = c < key ? c : key;
        }

        for (int it = 0; it < KSEL; ++it) {
            ull m = key;
            #pragma unroll
            for (int off = 1; off < 64; off <<= 1) {
                ull o = __shfl_xor(m, off);
                m = o < m ? o : m;
            }
            if (lane == 0) wl[wid][it] = m;
            if (key == m) {                         // unique winner
                unsigned rl = (unsigned)(m & 0xffffffffu) - (unsigned)(sc * CHUNK);
                mask |= 1u << (rl >> 7);
                ull nk = ~0ull;
                #pragma unroll
                for (int j = 0; j < 16; ++j) {
                    if (!((mask >> j) & 1u)) {
                        ull c = ((ull)__float_as_uint(d2v[j]) << 32) |
                                (unsigned)(base + j * 128);
                        nk = c < nk ? c : nk;
                    }
                }
                key = nk;
            }
        }
    }
    __syncthreads();

    // ---- merge the two sorted wave lists per query -> sorted chunk top-32
    if (tid < QG) {
        const int q = tid;
        const ull* A = wl[2 * q];
        const ull* B = wl[2 * q + 1];
        int ia = 0, ib = 0;
        ull* dst = cand + ((size_t)(qg * QG + q) * NCH + sc) * KSEL;
        for (int i = 0; i < KSEL; ++i) {
            ull ka = (ia < KSEL) ? A[ia] : ~0ull;
            ull kb = (ib < KSEL) ? B[ib] : ~0ull;
            if (ka < kb) { dst[i] = ka; ++ia; }
            else         { dst[i] = kb; ++ib; }
        }
    }
}

// ---------------------------------------------------------------------------
// Phase B: wave per query; lanes 0..7 do an 8-way sorted-list merge of the
// per-chunk candidates; lane 0 accumulates the softmax online.
__global__ __launch_bounds__(256) void knn_phaseB(
    const ull* __restrict__ cand, const float* __restrict__ labels,
    float* __restrict__ out)
{
    const int lane = threadIdx.x & 63;
    const int wid  = threadIdx.x >> 6;
    const int q    = blockIdx.x * 4 + wid;

    const ull* lst = cand + ((size_t)q * NCH + (lane & 7)) * KSEL;
    int ptr = 0;
    ull cur = (lane < NCH) ? lst[0] : ~0ull;

    float d0 = 0.0f, sw = 0.0f, sl = 0.0f;
    for (int it = 0; it < KSEL; ++it) {
        ull m = cur;
        #pragma unroll
        for (int off = 1; off < 8; off <<= 1) {
            ull o = __shfl_xor(m, off);
            m = o < m ? o : m;
        }
        if (lane < NCH && cur == m) {
            ++ptr;
            cur = (ptr < KSEL) ? lst[ptr] : ~0ull;
        }
        if (lane == 0) {
            float d = sqrtf(__uint_as_float((unsigned)(m >> 32)));
            if (it == 0) d0 = d;
            float w = expf((d0 - d) * INV_T);
            sw += w;
            sl += w * labels[(unsigned)(m & 0xffffffffu)];
        }
    }
    if (lane == 0) out[q] = sl / sw;
}

// ---------------------------------------------------------------------------
extern "C" void kernel_launch(void* const* d_in, const int* in_sizes, int n_in,
                              void* d_out, int out_size, void* d_ws, size_t ws_size,
                              hipStream_t stream) {
    const float* x      = (const float*)d_in[0];   // [256,256]
    const float* sx     = (const float*)d_in[1];   // [16384,256]
    const float* labels = (const float*)d_in[2];   // [16384,1]
    const float* W1     = (const float*)d_in[3];   // [64,256]
    const float* b1     = (const float*)d_in[4];
    const float* W2     = (const float*)d_in[5];   // [64,64]
    const float* b2     = (const float*)d_in[6];
    const float* W3     = (const float*)d_in[7];   // [64,64]
    const float* b3     = (const float*)d_in[8];
    float* out = (float*)d_out;

    float* ws     = (float*)d_ws;
    float* s_emb  = ws;                            // 16384*64
    float* s_norm = s_emb + N_SUP * D_E;           // 16384
    float* q_emb  = s_norm + N_SUP;                // 256*64
    float* q_norm = q_emb + NQ * D_E;              // 256
    float* W1T    = q_norm + NQ;                   // 256*64
    float* W2T    = W1T + D_IN * D_E;              // 64*64
    float* W3T    = W2T + D_E * D_E;               // 64*64
    ull*   cand   = (ull*)(W3T + D_E * D_E);       // 256*8*32 ull (offset 8B-aligned)

    prep_transpose<<<3, 1024, 0, stream>>>(W1, W2, W3, W1T, W2T, W3T);
    embed_kernel<<<(N_SUP + NQ) / 64, 256, 0, stream>>>(
        sx, x, W1T, b1, W2T, b2, W3T, b3, s_emb, s_norm, q_emb, q_norm);
    knn_phaseA<<<NQG * NCH, 1024, 0, stream>>>(s_emb, s_norm, q_emb, q_norm, cand);
    knn_phaseB<<<NQ / 4, 256, 0, stream>>>(cand, labels, out);
}

// Round 4
// 132.782 us; speedup vs baseline: 3.6458x; 1.2063x over previous
//
#include <hip/hip_runtime.h>
#include <math.h>

#define D_IN   256
#define D_E    64
#define N_SUP  16384
#define NQ     256
#define KSEL   32
#define RTOLC  1e-5f
#define ATOLC  1e-5f
#define INV_T  10.0f    // 1/TEMPERATURE

#define CHUNK  1024     // support rows per phase-A block
#define NCH    16       // support chunks
#define QG     8        // queries per phase-A block
#define NQG    32       // query groups

typedef unsigned long long ull;

__device__ __forceinline__ float gelu_exact(float x) {
    return 0.5f * x * (1.0f + erff(x * 0.70710678118654752440f));
}

// ---------------------------------------------------------------------------
// Embed: 260 blocks x 512 threads (8 waves). 64 rows/block (lane = row), wave
// w computes features [8w, 8w+8). Weights read at wave-uniform addresses
// (s_load, no transpose prep); x staged transposed in LDS (pad 65).
__global__ __launch_bounds__(512, 2) void embed_kernel(
    const float* __restrict__ sx, const float* __restrict__ x,
    const float* __restrict__ W1, const float* __restrict__ b1,
    const float* __restrict__ W2, const float* __restrict__ b2,
    const float* __restrict__ W3, const float* __restrict__ b3,
    float* __restrict__ s_emb, float* __restrict__ s_norm,
    float* __restrict__ q_emb, float* __restrict__ q_norm)
{
    __shared__ float xT[D_IN][65];    // ~66.6 KB
    __shared__ float hA[D_E][65];
    __shared__ float hB[D_E][65];
    __shared__ float nsum[64][9];

    const int tid  = threadIdx.x;
    const int lane = tid & 63;
    const int wv   = tid >> 6;
    const int f0   = __builtin_amdgcn_readfirstlane(wv * 8);
    const bool isq = blockIdx.x >= (N_SUP / 64);
    const float* src = isq ? (x + (size_t)(blockIdx.x - N_SUP / 64) * 64 * D_IN)
                           : (sx + (size_t)blockIdx.x * 64 * D_IN);

    // stage x transposed (coalesced float4 loads; writes ~8-way spread by pad)
    #pragma unroll
    for (int i = 0; i < 8; ++i) {
        int f4 = tid + 512 * i;
        float4 v = *reinterpret_cast<const float4*>(src + (size_t)f4 * 4);
        int row = f4 >> 6;
        int k0  = (f4 & 63) * 4;
        xT[k0 + 0][row] = v.x; xT[k0 + 1][row] = v.y;
        xT[k0 + 2][row] = v.z; xT[k0 + 3][row] = v.w;
    }
    __syncthreads();

    // ---- layer 1 (k ascending per feature: same fp32 chain as R3)
    float acc[8];
    #pragma unroll
    for (int i = 0; i < 8; ++i) acc[i] = b1[f0 + i];
    #pragma unroll 2
    for (int k0 = 0; k0 < D_IN; k0 += 8) {
        float xk[8];
        #pragma unroll
        for (int j = 0; j < 8; ++j) xk[j] = xT[k0 + j][lane];
        #pragma unroll
        for (int f = 0; f < 8; ++f) {
            const float* wr = W1 + (size_t)(f0 + f) * D_IN + k0;   // uniform
            #pragma unroll
            for (int j = 0; j < 8; ++j) acc[f] = fmaf(wr[j], xk[j], acc[f]);
        }
    }
    #pragma unroll
    for (int i = 0; i < 8; ++i) hA[f0 + i][lane] = gelu_exact(acc[i]);
    __syncthreads();

    // ---- layer 2
    float a2[8];
    #pragma unroll
    for (int i = 0; i < 8; ++i) a2[i] = b2[f0 + i];
    #pragma unroll 2
    for (int k0 = 0; k0 < D_E; k0 += 8) {
        float xk[8];
        #pragma unroll
        for (int j = 0; j < 8; ++j) xk[j] = hA[k0 + j][lane];
        #pragma unroll
        for (int f = 0; f < 8; ++f) {
            const float* wr = W2 + (size_t)(f0 + f) * D_E + k0;    // uniform
            #pragma unroll
            for (int j = 0; j < 8; ++j) a2[f] = fmaf(wr[j], xk[j], a2[f]);
        }
    }
    #pragma unroll
    for (int i = 0; i < 8; ++i) hB[f0 + i][lane] = gelu_exact(a2[i]);
    __syncthreads();

    // ---- layer 3 + sigmoid + norm
    float a3[8];
    #pragma unroll
    for (int i = 0; i < 8; ++i) a3[i] = b3[f0 + i];
    #pragma unroll 2
    for (int k0 = 0; k0 < D_E; k0 += 8) {
        float xk[8];
        #pragma unroll
        for (int j = 0; j < 8; ++j) xk[j] = hB[k0 + j][lane];
        #pragma unroll
        for (int f = 0; f < 8; ++f) {
            const float* wr = W3 + (size_t)(f0 + f) * D_E + k0;    // uniform
            #pragma unroll
            for (int j = 0; j < 8; ++j) a3[f] = fmaf(wr[j], xk[j], a3[f]);
        }
    }
    float e[8];
    float np = 0.0f;
    #pragma unroll
    for (int i = 0; i < 8; ++i) {
        e[i] = 1.0f / (1.0f + expf(-a3[i]));
        np = fmaf(e[i], e[i], np);
    }

    const int rowl = isq ? (blockIdx.x - N_SUP / 64) * 64 + lane
                         : blockIdx.x * 64 + lane;
    float* E   = isq ? q_emb  : s_emb;
    float* Nrm = isq ? q_norm : s_norm;
    float* erow = E + (size_t)rowl * D_E + f0;
    *reinterpret_cast<float4*>(erow)     = make_float4(e[0], e[1], e[2], e[3]);
    *reinterpret_cast<float4*>(erow + 4) = make_float4(e[4], e[5], e[6], e[7]);

    nsum[lane][wv] = np;
    __syncthreads();
    if (wv == 0) {
        float s = 0.0f;
        #pragma unroll
        for (int w = 0; w < 8; ++w) s += nsum[lane][w];
        Nrm[rowl] = s;
    }
}

// ---------------------------------------------------------------------------
// Phase A: grid = NQG*NCH = 512 blocks (qg = b>>4, sc = b&15), 512 threads.
// Distance phase: thread t computes d^2 for rows 2t,2t+1 x 8 queries into LDS.
// Selection: wave w owns query w; 16 d2 values/lane in registers; 32 rounds of
// wave-argmin over packed u64 key (d2bits<<10 | local_row) -- exact (d2,index)
// lexicographic min, chain depth 6 bpermute-pairs/round. Winner streams sorted
// directly to global from lane 0.
__global__ __launch_bounds__(512, 4) void knn_phaseA(
    const float* __restrict__ s_emb, const float* __restrict__ s_norm,
    const float* __restrict__ q_emb, const float* __restrict__ q_norm,
    ull* __restrict__ cand)
{
    __shared__ __align__(16) float qs[QG][D_E];
    __shared__ float qn_l[QG];
    __shared__ float d2lds[QG][CHUNK];          // 32 KB

    const int tid  = threadIdx.x;
    const int lane = tid & 63;
    const int wid  = tid >> 6;
    const int qg   = blockIdx.x >> 4;
    const int sc   = blockIdx.x & 15;

    ((float*)qs)[tid] = q_emb[qg * QG * D_E + tid];   // 512 == QG*D_E
    if (tid < QG) qn_l[tid] = q_norm[qg * QG + tid];
    __syncthreads();

    // ---- distances
    {
        const int r0  = 2 * tid;
        const int gr0 = sc * CHUNK + r0;
        const float* s0 = s_emb + (size_t)gr0 * D_E;
        const float* s1 = s0 + D_E;
        float acc0[QG], acc1[QG];
        #pragma unroll
        for (int q = 0; q < QG; ++q) { acc0[q] = 0.0f; acc1[q] = 0.0f; }
        #pragma unroll 4
        for (int kq = 0; kq < 16; ++kq) {
            float4 a = *reinterpret_cast<const float4*>(s0 + kq * 4);
            float4 b = *reinterpret_cast<const float4*>(s1 + kq * 4);
            #pragma unroll
            for (int q = 0; q < QG; ++q) {
                float4 qv = *reinterpret_cast<const float4*>(&qs[q][kq * 4]);
                acc0[q] = fmaf(qv.x, a.x, acc0[q]);
                acc0[q] = fmaf(qv.y, a.y, acc0[q]);
                acc0[q] = fmaf(qv.z, a.z, acc0[q]);
                acc0[q] = fmaf(qv.w, a.w, acc0[q]);
                acc1[q] = fmaf(qv.x, b.x, acc1[q]);
                acc1[q] = fmaf(qv.y, b.y, acc1[q]);
                acc1[q] = fmaf(qv.z, b.z, acc1[q]);
                acc1[q] = fmaf(qv.w, b.w, acc1[q]);
            }
        }
        const float sn0 = s_norm[gr0];
        const float sn1 = s_norm[gr0 + 1];
        #pragma unroll
        for (int q = 0; q < QG; ++q) {
            float d2a = fmaxf(qn_l[q] + sn0 - 2.0f * acc0[q], 0.0f);
            float d2b = fmaxf(qn_l[q] + sn1 - 2.0f * acc1[q], 0.0f);
            if (d2a < 1e-2f) {          // possible isclose duplicate (slack gate)
                bool close = true;
                for (int k = 0; k < D_E; ++k) {
                    float sv = s0[k];
                    close = close && (fabsf(qs[q][k] - sv) <= (ATOLC + RTOLC * fabsf(sv)));
                }
                if (close) d2a = INFINITY;
            }
            if (d2b < 1e-2f) {
                bool close = true;
                for (int k = 0; k < D_E; ++k) {
                    float sv = s1[k];
                    close = close && (fabsf(qs[q][k] - sv) <= (ATOLC + RTOLC * fabsf(sv)));
                }
                if (close) d2b = INFINITY;
            }
            d2lds[q][r0]     = d2a;
            d2lds[q][r0 + 1] = d2b;
        }
    }
    __syncthreads();

    // ---- per-wave top-32 for query `wid`
    float v[16];
    #pragma unroll
    for (int j = 0; j < 16; ++j) v[j] = d2lds[wid][j * 64 + lane];

    float    lmin = v[0];
    unsigned lrow = (unsigned)lane;               // local row = j*64 + lane
    #pragma unroll
    for (int j = 1; j < 16; ++j) {
        bool b = v[j] < lmin;
        lmin = b ? v[j] : lmin;
        lrow = b ? (unsigned)(j * 64 + lane) : lrow;
    }
    ull lkey = ((ull)__float_as_uint(lmin) << 10) | (ull)lrow;
    unsigned kmask = 0;
    ull* dst = cand + ((size_t)(qg * QG + wid) * NCH + sc) * KSEL;

    for (int it = 0; it < KSEL; ++it) {
        ull m = lkey;
        #pragma unroll
        for (int off = 1; off < 64; off <<= 1) {
            ull o = __shfl_xor(m, off);
            m = o < m ? o : m;
        }
        if (lane == 0)
            dst[it] = ((m >> 10) << 32) | (ull)(unsigned)(sc * CHUNK + (unsigned)(m & 1023u));
        if (lkey == m) {                           // unique winner lane
            kmask |= 1u << ((unsigned)(m & 1023u) >> 6);
            float    nm = INFINITY;
            unsigned nr = 1023u;
            #pragma unroll
            for (int j = 0; j < 16; ++j) {
                if (!((kmask >> j) & 1u)) {
                    bool b = v[j] < nm;
                    nm = b ? v[j] : nm;
                    nr = b ? (unsigned)(j * 64 + lane) : nr;
                }
            }
            lmin = nm; lrow = nr;
            lkey = ((ull)__float_as_uint(nm) << 10) | (ull)nr;
        }
    }
}

// ---------------------------------------------------------------------------
// Phase B: wave per query; lanes 0..15 do a 16-way sorted-list merge of the
// per-chunk candidates; lane 0 accumulates the softmax online.
__global__ __launch_bounds__(256) void knn_phaseB(
    const ull* __restrict__ cand, const float* __restrict__ labels,
    float* __restrict__ out)
{
    const int lane = threadIdx.x & 63;
    const int wid  = threadIdx.x >> 6;
    const int q    = blockIdx.x * 4 + wid;

    const ull* lst = cand + ((size_t)q * NCH + (lane & 15)) * KSEL;
    int ptr = 0;
    ull cur = (lane < NCH) ? lst[0] : ~0ull;

    float d0 = 0.0f, sw = 0.0f, sl = 0.0f;
    for (int it = 0; it < KSEL; ++it) {
        ull m = cur;
        #pragma unroll
        for (int off = 1; off < 16; off <<= 1) {    // min over lanes 0..15
            ull o = __shfl_xor(m, off);
            m = o < m ? o : m;
        }
        if (lane < NCH && cur == m) {
            ++ptr;
            cur = (ptr < KSEL) ? lst[ptr] : ~0ull;
        }
        if (lane == 0) {
            unsigned idx = (unsigned)(m & 0xffffffffu);
            float d = sqrtf(__uint_as_float((unsigned)(m >> 32)));
            if (it == 0) d0 = d;
            float w = expf((d0 - d) * INV_T);
            sw += w;
            sl += w * labels[idx < N_SUP ? idx : 0];
        }
    }
    if (lane == 0) out[q] = sl / sw;
}

// ---------------------------------------------------------------------------
extern "C" void kernel_launch(void* const* d_in, const int* in_sizes, int n_in,
                              void* d_out, int out_size, void* d_ws, size_t ws_size,
                              hipStream_t stream) {
    const float* x      = (const float*)d_in[0];   // [256,256]
    const float* sx     = (const float*)d_in[1];   // [16384,256]
    const float* labels = (const float*)d_in[2];   // [16384,1]
    const float* W1     = (const float*)d_in[3];   // [64,256]
    const float* b1     = (const float*)d_in[4];
    const float* W2     = (const float*)d_in[5];   // [64,64]
    const float* b2     = (const float*)d_in[6];
    const float* W3     = (const float*)d_in[7];   // [64,64]
    const float* b3     = (const float*)d_in[8];
    float* out = (float*)d_out;

    float* ws     = (float*)d_ws;
    float* s_emb  = ws;                            // 16384*64
    float* s_norm = s_emb + N_SUP * D_E;           // 16384
    float* q_emb  = s_norm + N_SUP;                // 256*64
    float* q_norm = q_emb + NQ * D_E;              // 256
    ull*   cand   = (ull*)(q_norm + NQ);           // 256*16*32 ull (8B-aligned)

    embed_kernel<<<(N_SUP + NQ) / 64, 512, 0, stream>>>(
        sx, x, W1, b1, W2, b2, W3, b3, s_emb, s_norm, q_emb, q_norm);
    knn_phaseA<<<NQG * NCH, 512, 0, stream>>>(s_emb, s_norm, q_emb, q_norm, cand);
    knn_phaseB<<<NQ / 4, 256, 0, stream>>>(cand, labels, out);
}

// Round 5
// 107.049 us; speedup vs baseline: 4.5222x; 1.2404x over previous
//
#include <hip/hip_runtime.h>
#include <math.h>

#define D_IN   256
#define D_E    64
#define N_SUP  16384
#define NQ     256
#define KSEL   32
#define RTOLC  1e-5f
#define ATOLC  1e-5f
#define INV_T  10.0f    // 1/TEMPERATURE

#define CHUNK  1024     // support rows per phase-A block
#define NCH    16       // support chunks
#define QG     8        // queries per phase-A block
#define NQG    32       // query groups

typedef unsigned long long ull;

__device__ __forceinline__ float gelu_exact(float x) {
    return 0.5f * x * (1.0f + erff(x * 0.70710678118654752440f));
}

// ---------------------------------------------------------------------------
// Prep: transpose weights so embed's k-loop does one uniform s_load per k.
__global__ __launch_bounds__(256) void prep_w(
    const float* __restrict__ W1, const float* __restrict__ W2,
    const float* __restrict__ W3,
    float* __restrict__ W1T, float* __restrict__ W2T, float* __restrict__ W3T)
{
    const int t = blockIdx.x * 256 + threadIdx.x;
    const int stride = gridDim.x * 256;
    for (int o = t; o < D_E * D_IN; o += stride) {
        int f = o >> 8, k = o & 255;
        W1T[k * D_E + f] = W1[o];
    }
    for (int o = t; o < D_E * D_E; o += stride) {
        int f = o >> 6, k = o & 63;
        W2T[k * D_E + f] = W2[o];
        W3T[k * D_E + f] = W3[o];
    }
}

// ---------------------------------------------------------------------------
// Embed: 260 blocks x 512 threads (8 waves), 64 rows/block (lane = row),
// wave w computes features [8w, 8w+8). x transposed in 64x64 LDS chunks
// (16.6 KB) -> total LDS ~51 KB -> 3 blocks/CU. Weights via uniform s_load
// of the pre-transposed W*T. Summation order: k ascending (same as R4).
__global__ __launch_bounds__(512, 6) void embed_kernel(
    const float* __restrict__ sx, const float* __restrict__ x,
    const float* __restrict__ W1T, const float* __restrict__ b1,
    const float* __restrict__ W2T, const float* __restrict__ b2,
    const float* __restrict__ W3T, const float* __restrict__ b3,
    float* __restrict__ s_emb, float* __restrict__ s_norm,
    float* __restrict__ q_emb, float* __restrict__ q_norm)
{
    __shared__ float xc[64][65];     // one 64-k chunk, transposed [k][row]
    __shared__ float hA[64][65];
    __shared__ float hB[64][65];
    __shared__ float nsum[64][9];

    const int tid  = threadIdx.x;
    const int lane = tid & 63;
    const int wv   = tid >> 6;
    const int f0   = __builtin_amdgcn_readfirstlane(wv * 8);
    const bool isq = blockIdx.x >= (N_SUP / 64);
    const float* src = isq ? (x + (size_t)(blockIdx.x - N_SUP / 64) * 64 * D_IN)
                           : (sx + (size_t)blockIdx.x * 64 * D_IN);

    // ---- layer 1 over 4 k-chunks of 64
    float acc[8];
    #pragma unroll
    for (int i = 0; i < 8; ++i) acc[i] = b1[f0 + i];

    for (int kc = 0; kc < 4; ++kc) {
        __syncthreads();                       // prev chunk fully consumed
        #pragma unroll
        for (int i = 0; i < 2; ++i) {
            int g   = i * 512 + tid;           // float4 id in [0,1024)
            int row = g >> 4;
            int c4  = g & 15;
            float4 v = *reinterpret_cast<const float4*>(
                src + (size_t)row * D_IN + kc * 64 + c4 * 4);
            xc[c4 * 4 + 0][row] = v.x; xc[c4 * 4 + 1][row] = v.y;
            xc[c4 * 4 + 2][row] = v.z; xc[c4 * 4 + 3][row] = v.w;
        }
        __syncthreads();
        const float* wbase = W1T + (size_t)(kc * 64) * D_E + f0;
        #pragma unroll 8
        for (int k = 0; k < 64; ++k) {
            float xk = xc[k][lane];
            const float* wk = wbase + k * D_E;          // uniform -> s_load
            #pragma unroll
            for (int f = 0; f < 8; ++f) acc[f] = fmaf(wk[f], xk, acc[f]);
        }
    }
    #pragma unroll
    for (int i = 0; i < 8; ++i) hA[f0 + i][lane] = gelu_exact(acc[i]);
    __syncthreads();

    // ---- layer 2
    float a2[8];
    #pragma unroll
    for (int i = 0; i < 8; ++i) a2[i] = b2[f0 + i];
    #pragma unroll 8
    for (int k = 0; k < D_E; ++k) {
        float hk = hA[k][lane];
        const float* wk = W2T + k * D_E + f0;           // uniform -> s_load
        #pragma unroll
        for (int f = 0; f < 8; ++f) a2[f] = fmaf(wk[f], hk, a2[f]);
    }
    #pragma unroll
    for (int i = 0; i < 8; ++i) hB[f0 + i][lane] = gelu_exact(a2[i]);
    __syncthreads();

    // ---- layer 3 + sigmoid + norm
    float a3[8];
    #pragma unroll
    for (int i = 0; i < 8; ++i) a3[i] = b3[f0 + i];
    #pragma unroll 8
    for (int k = 0; k < D_E; ++k) {
        float hk = hB[k][lane];
        const float* wk = W3T + k * D_E + f0;           // uniform -> s_load
        #pragma unroll
        for (int f = 0; f < 8; ++f) a3[f] = fmaf(wk[f], hk, a3[f]);
    }
    float e[8];
    float np = 0.0f;
    #pragma unroll
    for (int i = 0; i < 8; ++i) {
        e[i] = 1.0f / (1.0f + expf(-a3[i]));
        np = fmaf(e[i], e[i], np);
    }

    const int rowl = isq ? (blockIdx.x - N_SUP / 64) * 64 + lane
                         : blockIdx.x * 64 + lane;
    float* E   = isq ? q_emb  : s_emb;
    float* Nrm = isq ? q_norm : s_norm;
    float* erow = E + (size_t)rowl * D_E + f0;
    *reinterpret_cast<float4*>(erow)     = make_float4(e[0], e[1], e[2], e[3]);
    *reinterpret_cast<float4*>(erow + 4) = make_float4(e[4], e[5], e[6], e[7]);

    nsum[lane][wv] = np;
    __syncthreads();
    if (wv == 0) {
        float s = 0.0f;
        #pragma unroll
        for (int w = 0; w < 8; ++w) s += nsum[lane][w];
        Nrm[rowl] = s;
    }
}

// ---------------------------------------------------------------------------
// Phase A: grid 512 (qg = b>>4, sc = b&15), 512 threads, 2 blocks/CU.
// 8 stages of 128 rows staged coalesced into LDS (row stride 272 B).
// Thread = (row rl = tid&127, query-pair qp = tid>>7, wave-uniform).
// Queries read via uniform scalar loads -> v_fmac with SGPR operand.
// Selection identical to R4 (absmax 0): per-wave top-32, packed u64 keys.
__global__ __launch_bounds__(512, 4) void knn_phaseA(
    const float* __restrict__ s_emb, const float* __restrict__ s_norm,
    const float* __restrict__ q_emb, const float* __restrict__ q_norm,
    ull* __restrict__ cand)
{
    __shared__ float tile[128 * 68];            // 34.8 KB, stride 68 dwords
    __shared__ float d2l[QG][CHUNK];            // 32 KB

    const int tid  = threadIdx.x;
    const int lane = tid & 63;
    const int wid  = tid >> 6;
    const int qg   = blockIdx.x >> 4;
    const int sc   = blockIdx.x & 15;

    const int qp = __builtin_amdgcn_readfirstlane(tid >> 7);   // 0..3
    const float* q0 = q_emb + (size_t)(qg * QG + 2 * qp) * D_E;
    const float* q1 = q0 + D_E;
    const float qn0 = q_norm[qg * QG + 2 * qp];
    const float qn1 = q_norm[qg * QG + 2 * qp + 1];
    const int rl = tid & 127;

    for (int s = 0; s < 8; ++s) {
        __syncthreads();
        #pragma unroll
        for (int i = 0; i < 4; ++i) {
            int g   = i * 512 + tid;            // float4 id in [0,2048)
            int row = g >> 4, c4 = g & 15;
            float4 v = *reinterpret_cast<const float4*>(
                s_emb + (size_t)(sc * CHUNK + s * 128 + row) * D_E + c4 * 4);
            *reinterpret_cast<float4*>(&tile[row * 68 + c4 * 4]) = v;
        }
        __syncthreads();

        const float* tr = &tile[rl * 68];
        float a0 = 0.0f, a1 = 0.0f;
        #pragma unroll
        for (int c = 0; c < 16; ++c) {
            float4 sv = *reinterpret_cast<const float4*>(tr + c * 4);
            a0 = fmaf(q0[c * 4 + 0], sv.x, a0);
            a0 = fmaf(q0[c * 4 + 1], sv.y, a0);
            a0 = fmaf(q0[c * 4 + 2], sv.z, a0);
            a0 = fmaf(q0[c * 4 + 3], sv.w, a0);
            a1 = fmaf(q1[c * 4 + 0], sv.x, a1);
            a1 = fmaf(q1[c * 4 + 1], sv.y, a1);
            a1 = fmaf(q1[c * 4 + 2], sv.z, a1);
            a1 = fmaf(q1[c * 4 + 3], sv.w, a1);
        }
        const int grow = sc * CHUNK + s * 128 + rl;
        const float sn = s_norm[grow];
        float d20 = fmaxf(qn0 + sn - 2.0f * a0, 0.0f);
        float d21 = fmaxf(qn1 + sn - 2.0f * a1, 0.0f);
        if (d20 < 1e-2f) {      // possible isclose duplicate (slack gate)
            bool close = true;
            for (int k = 0; k < D_E; ++k) {
                float sv = tr[k];
                close = close && (fabsf(q0[k] - sv) <= (ATOLC + RTOLC * fabsf(sv)));
            }
            if (close) d20 = INFINITY;
        }
        if (d21 < 1e-2f) {
            bool close = true;
            for (int k = 0; k < D_E; ++k) {
                float sv = tr[k];
                close = close && (fabsf(q1[k] - sv) <= (ATOLC + RTOLC * fabsf(sv)));
            }
            if (close) d21 = INFINITY;
        }
        d2l[2 * qp][s * 128 + rl]     = d20;
        d2l[2 * qp + 1][s * 128 + rl] = d21;
    }
    __syncthreads();

    // ---- per-wave top-32 for query `wid` (identical to R4)
    float v[16];
    #pragma unroll
    for (int j = 0; j < 16; ++j) v[j] = d2l[wid][j * 64 + lane];

    float    lmin = v[0];
    unsigned lrow = (unsigned)lane;
    #pragma unroll
    for (int j = 1; j < 16; ++j) {
        bool b = v[j] < lmin;
        lmin = b ? v[j] : lmin;
        lrow = b ? (unsigned)(j * 64 + lane) : lrow;
    }
    ull lkey = ((ull)__float_as_uint(lmin) << 10) | (ull)lrow;
    unsigned kmask = 0;
    ull* dst = cand + ((size_t)(qg * QG + wid) * NCH + sc) * KSEL;

    for (int it = 0; it < KSEL; ++it) {
        ull m = lkey;
        #pragma unroll
        for (int off = 1; off < 64; off <<= 1) {
            ull o = __shfl_xor(m, off);
            m = o < m ? o : m;
        }
        if (lane == 0)
            dst[it] = ((m >> 10) << 32) | (ull)(unsigned)(sc * CHUNK + (unsigned)(m & 1023u));
        if (lkey == m) {                         // unique winner lane
            kmask |= 1u << ((unsigned)(m & 1023u) >> 6);
            float    nm = INFINITY;
            unsigned nr = 1023u;
            #pragma unroll
            for (int j = 0; j < 16; ++j) {
                if (!((kmask >> j) & 1u)) {
                    bool b = v[j] < nm;
                    nm = b ? v[j] : nm;
                    nr = b ? (unsigned)(j * 64 + lane) : nr;
                }
            }
            lmin = nm; lrow = nr;
            lkey = ((ull)__float_as_uint(nm) << 10) | (ull)nr;
        }
    }
}

// ---------------------------------------------------------------------------
// Phase B: wave per query; lanes 0..15 merge the 16 sorted chunk lists;
// lane 0 accumulates the softmax online. Identical to R4.
__global__ __launch_bounds__(256) void knn_phaseB(
    const ull* __restrict__ cand, const float* __restrict__ labels,
    float* __restrict__ out)
{
    const int lane = threadIdx.x & 63;
    const int wid  = threadIdx.x >> 6;
    const int q    = blockIdx.x * 4 + wid;

    const ull* lst = cand + ((size_t)q * NCH + (lane & 15)) * KSEL;
    int ptr = 0;
    ull cur = (lane < NCH) ? lst[0] : ~0ull;

    float d0 = 0.0f, sw = 0.0f, sl = 0.0f;
    for (int it = 0; it < KSEL; ++it) {
        ull m = cur;
        #pragma unroll
        for (int off = 1; off < 16; off <<= 1) {
            ull o = __shfl_xor(m, off);
            m = o < m ? o : m;
        }
        if (lane < NCH && cur == m) {
            ++ptr;
            cur = (ptr < KSEL) ? lst[ptr] : ~0ull;
        }
        if (lane == 0) {
            unsigned idx = (unsigned)(m & 0xffffffffu);
            float d = sqrtf(__uint_as_float((unsigned)(m >> 32)));
            if (it == 0) d0 = d;
            float w = expf((d0 - d) * INV_T);
            sw += w;
            sl += w * labels[idx < N_SUP ? idx : 0];
        }
    }
    if (lane == 0) out[q] = sl / sw;
}

// ---------------------------------------------------------------------------
extern "C" void kernel_launch(void* const* d_in, const int* in_sizes, int n_in,
                              void* d_out, int out_size, void* d_ws, size_t ws_size,
                              hipStream_t stream) {
    const float* x      = (const float*)d_in[0];   // [256,256]
    const float* sx     = (const float*)d_in[1];   // [16384,256]
    const float* labels = (const float*)d_in[2];   // [16384,1]
    const float* W1     = (const float*)d_in[3];   // [64,256]
    const float* b1     = (const float*)d_in[4];
    const float* W2     = (const float*)d_in[5];   // [64,64]
    const float* b2     = (const float*)d_in[6];
    const float* W3     = (const float*)d_in[7];   // [64,64]
    const float* b3     = (const float*)d_in[8];
    float* out = (float*)d_out;

    float* ws     = (float*)d_ws;
    float* s_emb  = ws;                            // 16384*64
    float* s_norm = s_emb + N_SUP * D_E;           // 16384
    float* q_emb  = s_norm + N_SUP;                // 256*64
    float* q_norm = q_emb + NQ * D_E;              // 256
    float* W1T    = q_norm + NQ;                   // 256*64
    float* W2T    = W1T + D_IN * D_E;              // 64*64
    float* W3T    = W2T + D_E * D_E;               // 64*64
    ull*   cand   = (ull*)(W3T + D_E * D_E);       // 256*16*32 ull

    prep_w<<<32, 256, 0, stream>>>(W1, W2, W3, W1T, W2T, W3T);
    embed_kernel<<<(N_SUP + NQ) / 64, 512, 0, stream>>>(
        sx, x, W1T, b1, W2T, b2, W3T, b3, s_emb, s_norm, q_emb, q_norm);
    knn_phaseA<<<NQG * NCH, 512, 0, stream>>>(s_emb, s_norm, q_emb, q_norm, cand);
    knn_phaseB<<<NQ / 4, 256, 0, stream>>>(cand, labels, out);
}

// Round 6
// 101.609 us; speedup vs baseline: 4.7644x; 1.0535x over previous
//
#include <hip/hip_runtime.h>
#include <math.h>

#define D_IN   256
#define D_E    64
#define N_SUP  16384
#define NQ     256
#define KSEL   32
#define RTOLC  1e-5f
#define ATOLC  1e-5f
#define INV_T  10.0f    // 1/TEMPERATURE

#define CHUNK  1024     // support rows per phase-A block
#define NCH    16       // support chunks
#define QG     8        // queries per phase-A block (= waves)
#define NQG    32       // query groups

typedef unsigned long long ull;

__device__ __forceinline__ float gelu_exact(float x) {
    return 0.5f * x * (1.0f + erff(x * 0.70710678118654752440f));
}

// ---------------------------------------------------------------------------
// Prep: transpose weights so embed's k-loop does one uniform s_load per k.
__global__ __launch_bounds__(256) void prep_w(
    const float* __restrict__ W1, const float* __restrict__ W2,
    const float* __restrict__ W3,
    float* __restrict__ W1T, float* __restrict__ W2T, float* __restrict__ W3T)
{
    const int t = blockIdx.x * 256 + threadIdx.x;
    const int stride = gridDim.x * 256;
    for (int o = t; o < D_E * D_IN; o += stride) {
        int f = o >> 8, k = o & 255;
        W1T[k * D_E + f] = W1[o];
    }
    for (int o = t; o < D_E * D_E; o += stride) {
        int f = o >> 6, k = o & 63;
        W2T[k * D_E + f] = W2[o];
        W3T[k * D_E + f] = W3[o];
    }
}

// ---------------------------------------------------------------------------
// Embed: unchanged from R5 (absmax 0). 260 blocks x 512 threads, 64 rows/block
// (lane = row), wave w computes features [8w, 8w+8), x transposed in 64-k LDS
// chunks, weights via uniform s_load of W*T.
__global__ __launch_bounds__(512, 6) void embed_kernel(
    const float* __restrict__ sx, const float* __restrict__ x,
    const float* __restrict__ W1T, const float* __restrict__ b1,
    const float* __restrict__ W2T, const float* __restrict__ b2,
    const float* __restrict__ W3T, const float* __restrict__ b3,
    float* __restrict__ s_emb, float* __restrict__ s_norm,
    float* __restrict__ q_emb, float* __restrict__ q_norm)
{
    __shared__ float xc[64][65];
    __shared__ float hA[64][65];
    __shared__ float hB[64][65];
    __shared__ float nsum[64][9];

    const int tid  = threadIdx.x;
    const int lane = tid & 63;
    const int wv   = tid >> 6;
    const int f0   = __builtin_amdgcn_readfirstlane(wv * 8);
    const bool isq = blockIdx.x >= (N_SUP / 64);
    const float* src = isq ? (x + (size_t)(blockIdx.x - N_SUP / 64) * 64 * D_IN)
                           : (sx + (size_t)blockIdx.x * 64 * D_IN);

    float acc[8];
    #pragma unroll
    for (int i = 0; i < 8; ++i) acc[i] = b1[f0 + i];

    for (int kc = 0; kc < 4; ++kc) {
        __syncthreads();
        #pragma unroll
        for (int i = 0; i < 2; ++i) {
            int g   = i * 512 + tid;
            int row = g >> 4;
            int c4  = g & 15;
            float4 v = *reinterpret_cast<const float4*>(
                src + (size_t)row * D_IN + kc * 64 + c4 * 4);
            xc[c4 * 4 + 0][row] = v.x; xc[c4 * 4 + 1][row] = v.y;
            xc[c4 * 4 + 2][row] = v.z; xc[c4 * 4 + 3][row] = v.w;
        }
        __syncthreads();
        const float* wbase = W1T + (size_t)(kc * 64) * D_E + f0;
        #pragma unroll 8
        for (int k = 0; k < 64; ++k) {
            float xk = xc[k][lane];
            const float* wk = wbase + k * D_E;
            #pragma unroll
            for (int f = 0; f < 8; ++f) acc[f] = fmaf(wk[f], xk, acc[f]);
        }
    }
    #pragma unroll
    for (int i = 0; i < 8; ++i) hA[f0 + i][lane] = gelu_exact(acc[i]);
    __syncthreads();

    float a2[8];
    #pragma unroll
    for (int i = 0; i < 8; ++i) a2[i] = b2[f0 + i];
    #pragma unroll 8
    for (int k = 0; k < D_E; ++k) {
        float hk = hA[k][lane];
        const float* wk = W2T + k * D_E + f0;
        #pragma unroll
        for (int f = 0; f < 8; ++f) a2[f] = fmaf(wk[f], hk, a2[f]);
    }
    #pragma unroll
    for (int i = 0; i < 8; ++i) hB[f0 + i][lane] = gelu_exact(a2[i]);
    __syncthreads();

    float a3[8];
    #pragma unroll
    for (int i = 0; i < 8; ++i) a3[i] = b3[f0 + i];
    #pragma unroll 8
    for (int k = 0; k < D_E; ++k) {
        float hk = hB[k][lane];
        const float* wk = W3T + k * D_E + f0;
        #pragma unroll
        for (int f = 0; f < 8; ++f) a3[f] = fmaf(wk[f], hk, a3[f]);
    }
    float e[8];
    float np = 0.0f;
    #pragma unroll
    for (int i = 0; i < 8; ++i) {
        e[i] = 1.0f / (1.0f + expf(-a3[i]));
        np = fmaf(e[i], e[i], np);
    }

    const int rowl = isq ? (blockIdx.x - N_SUP / 64) * 64 + lane
                         : blockIdx.x * 64 + lane;
    float* E   = isq ? q_emb  : s_emb;
    float* Nrm = isq ? q_norm : s_norm;
    float* erow = E + (size_t)rowl * D_E + f0;
    *reinterpret_cast<float4*>(erow)     = make_float4(e[0], e[1], e[2], e[3]);
    *reinterpret_cast<float4*>(erow + 4) = make_float4(e[4], e[5], e[6], e[7]);

    nsum[lane][wv] = np;
    __syncthreads();
    if (wv == 0) {
        float s = 0.0f;
        #pragma unroll
        for (int w = 0; w < 8; ++w) s += nsum[lane][w];
        Nrm[rowl] = s;
    }
}

// ---------------------------------------------------------------------------
// Phase A: grid 512 (qg = b>>4, sc = b&15), 512 threads, wave = query.
// 16 stages of 64 rows staged coalesced into LDS (stride 68: 0 conflicts, R5).
// Selection: bitonic-sort each lane's 16 (d2,row) u64 keys once, then 32
// rounds of wave-argmin; winner shifts its sorted list down (no rescan).
// Winners' labels fetched in parallel at the end; cand entry packs
// (d2bits<<32)|labelbits.
__global__ __launch_bounds__(512, 4) void knn_phaseA(
    const float* __restrict__ s_emb, const float* __restrict__ s_norm,
    const float* __restrict__ q_emb, const float* __restrict__ q_norm,
    const float* __restrict__ labels, ull* __restrict__ cand)
{
    __shared__ float tile[64 * 68];             // 17.4 KB
    __shared__ float d2l[QG][CHUNK];            // 32 KB
    __shared__ ull   win_l[QG][KSEL];           // 2 KB

    const int tid  = threadIdx.x;
    const int lane = tid & 63;
    const int wid  = tid >> 6;                  // wave = query within group
    const int qg   = blockIdx.x >> 4;
    const int sc   = blockIdx.x & 15;
    const int qiu  = __builtin_amdgcn_readfirstlane(qg * QG + wid);

    const float* q0 = q_emb + (size_t)qiu * D_E;   // uniform -> s_load
    const float  qn = q_norm[qiu];

    for (int s = 0; s < 16; ++s) {
        __syncthreads();
        #pragma unroll
        for (int i = 0; i < 2; ++i) {
            int g   = i * 512 + tid;            // float4 id in [0,1024)
            int row = g >> 4, c4 = g & 15;
            float4 v = *reinterpret_cast<const float4*>(
                s_emb + (size_t)(sc * CHUNK + s * 64 + row) * D_E + c4 * 4);
            *reinterpret_cast<float4*>(&tile[row * 68 + c4 * 4]) = v;
        }
        __syncthreads();

        const float* tr = &tile[lane * 68];
        float a = 0.0f;
        #pragma unroll
        for (int c = 0; c < 16; ++c) {
            float4 sv = *reinterpret_cast<const float4*>(tr + c * 4);
            a = fmaf(q0[c * 4 + 0], sv.x, a);
            a = fmaf(q0[c * 4 + 1], sv.y, a);
            a = fmaf(q0[c * 4 + 2], sv.z, a);
            a = fmaf(q0[c * 4 + 3], sv.w, a);
        }
        const int grow = sc * CHUNK + s * 64 + lane;
        float d2 = fmaxf(qn + s_norm[grow] - 2.0f * a, 0.0f);
        if (d2 < 1e-3f) {
            // possible isclose duplicate; true mask needs d2 <= 2.6e-8 and fp32
            // error on d2 is <= ~1e-5, so 1e-3 keeps 100x margin while making
            // this branch ~never-taken (the 1e-2 gate was the R5 VALU bloat)
            bool close = true;
            for (int k = 0; k < D_E; ++k) {
                float sv = tr[k];
                close = close && (fabsf(q0[k] - sv) <= (ATOLC + RTOLC * fabsf(sv)));
            }
            if (close) d2 = INFINITY;
        }
        d2l[wid][s * 64 + lane] = d2;
    }
    // d2l[wid] is written and read only by wave wid: no barrier needed.

    // ---- load + pack keys
    ull sk[16];
    #pragma unroll
    for (int j = 0; j < 16; ++j) {
        float d2 = d2l[wid][j * 64 + lane];
        sk[j] = ((ull)__float_as_uint(d2) << 10) | (unsigned)(j * 64 + lane);
    }

    // ---- bitonic sort 16 (ascending), all indices static
    #pragma unroll
    for (int k = 2; k <= 16; k <<= 1) {
        #pragma unroll
        for (int j = k >> 1; j > 0; j >>= 1) {
            #pragma unroll
            for (int i = 0; i < 16; ++i) {
                int ixj = i ^ j;
                if (ixj > i) {
                    if ((i & k) == 0) {
                        ull a_ = sk[i], b_ = sk[ixj];
                        bool c_ = b_ < a_;
                        sk[i] = c_ ? b_ : a_; sk[ixj] = c_ ? a_ : b_;
                    } else {
                        ull a_ = sk[i], b_ = sk[ixj];
                        bool c_ = a_ < b_;
                        sk[i] = c_ ? b_ : a_; sk[ixj] = c_ ? a_ : b_;
                    }
                }
            }
        }
    }

    // ---- 32 rounds of wave-argmin; winner shifts its list (no rescan)
    ull lkey = sk[0];
    for (int it = 0; it < KSEL; ++it) {
        ull m = lkey;
        #pragma unroll
        for (int off = 1; off < 64; off <<= 1) {
            ull o = __shfl_xor(m, off);
            m = o < m ? o : m;
        }
        if (lane == it) win_l[wid][it] = m;
        if (lkey == m) {                          // unique winner lane
            #pragma unroll
            for (int j = 0; j < 15; ++j) sk[j] = sk[j + 1];
            sk[15] = ~0ull;
            lkey = sk[0];
        }
    }

    // ---- parallel label fetch + emit (sorted by (d2, idx))
    if (lane < KSEL) {
        ull m = win_l[wid][lane];
        unsigned gidx = (unsigned)(sc * CHUNK) + (unsigned)(m & 1023u);
        float lab = labels[gidx];
        ull* dst = cand + ((size_t)qiu * NCH + sc) * KSEL;
        dst[lane] = ((ull)(unsigned)(m >> 10) << 32) | (ull)__float_as_uint(lab);
    }
}

// ---------------------------------------------------------------------------
// Phase B: wave per query; lanes 0..15 merge the 16 sorted chunk lists.
// Compare on d2bits with lower-lane tie-break (= lower chunk = lower global
// index, and within-list order is already (d2, idx) ascending: exact jax
// semantics). Labels ride in the candidate payload: zero scattered loads.
__global__ __launch_bounds__(256) void knn_phaseB(
    const ull* __restrict__ cand, float* __restrict__ out)
{
    const int lane = threadIdx.x & 63;
    const int wid  = threadIdx.x >> 6;
    const int q    = blockIdx.x * 4 + wid;

    const bool act = lane < NCH;
    const ull* lst = cand + ((size_t)q * NCH + (lane & 15)) * KSEL;
    int ptr = 0;
    ull cur = act ? lst[0] : ~0ull;

    float d0 = 0.0f, sw = 0.0f, sl = 0.0f;
    for (int it = 0; it < KSEL; ++it) {
        unsigned mv = (unsigned)(cur >> 32);
        unsigned ml = (unsigned)cur;
        #pragma unroll
        for (int off = 1; off < 16; off <<= 1) {
            unsigned ov = __shfl_xor(mv, off);
            unsigned ol = __shfl_xor(ml, off);
            bool take = (ov < mv) || (ov == mv && (lane & off));
            mv = take ? ov : mv;
            ml = take ? ol : ml;
        }
        ull b = __ballot(act && (unsigned)(cur >> 32) == mv);
        int wl = (int)(__ffsll((long long)b) - 1);     // lowest tied lane
        if (lane == wl) {
            ++ptr;
            cur = (ptr < KSEL) ? lst[ptr] : ~0ull;
        }
        if (lane == 0) {
            float d = sqrtf(__uint_as_float(mv));
            if (it == 0) d0 = d;
            float w = expf((d0 - d) * INV_T);
            sw += w;
            sl += w * __uint_as_float(ml);
        }
    }
    if (lane == 0) out[q] = sl / sw;
}

// ---------------------------------------------------------------------------
extern "C" void kernel_launch(void* const* d_in, const int* in_sizes, int n_in,
                              void* d_out, int out_size, void* d_ws, size_t ws_size,
                              hipStream_t stream) {
    const float* x      = (const float*)d_in[0];   // [256,256]
    const float* sx     = (const float*)d_in[1];   // [16384,256]
    const float* labels = (const float*)d_in[2];   // [16384,1]
    const float* W1     = (const float*)d_in[3];   // [64,256]
    const float* b1     = (const float*)d_in[4];
    const float* W2     = (const float*)d_in[5];   // [64,64]
    const float* b2     = (const float*)d_in[6];
    const float* W3     = (const float*)d_in[7];   // [64,64]
    const float* b3     = (const float*)d_in[8];
    float* out = (float*)d_out;

    float* ws     = (float*)d_ws;
    float* s_emb  = ws;                            // 16384*64
    float* s_norm = s_emb + N_SUP * D_E;           // 16384
    float* q_emb  = s_norm + N_SUP;                // 256*64
    float* q_norm = q_emb + NQ * D_E;              // 256
    float* W1T    = q_norm + NQ;                   // 256*64
    float* W2T    = W1T + D_IN * D_E;              // 64*64
    float* W3T    = W2T + D_E * D_E;               // 64*64
    ull*   cand   = (ull*)(W3T + D_E * D_E);       // 256*16*32 ull

    prep_w<<<32, 256, 0, stream>>>(W1, W2, W3, W1T, W2T, W3T);
    embed_kernel<<<(N_SUP + NQ) / 64, 512, 0, stream>>>(
        sx, x, W1T, b1, W2T, b2, W3T, b3, s_emb, s_norm, q_emb, q_norm);
    knn_phaseA<<<NQG * NCH, 512, 0, stream>>>(s_emb, s_norm, q_emb, q_norm,
                                              labels, cand);
    knn_phaseB<<<NQ / 4, 256, 0, stream>>>(cand, out);
}